// Round 4
// baseline (191.764 us; speedup 1.0000x reference)
//
#include <hip/hip_runtime.h>
#include <hip/hip_bf16.h>

typedef __attribute__((ext_vector_type(8))) short bf16x8;
typedef __attribute__((ext_vector_type(4))) float f32x4;

#define B_ROWS 8192
#define FDIM 128
#define BN 64            // cols per tile
#define NT 8             // tiles per block -> 512 cols per chunk
#define NCHUNK 16        // 8192 / 512

#define GLOAD_LDS(gp, lp) __builtin_amdgcn_global_load_lds( \
    (const __attribute__((address_space(1))) unsigned*)(gp), \
    (__attribute__((address_space(3))) unsigned*)(lp), 16, 0, 0)

#define LOG2E 1.4426950408889634f

// ---------------- Kernel A: normalize; z1n scaled by log2(e); pos[i] exact ----------------
__global__ __launch_bounds__(256) void simclr_norm(const float* __restrict__ z1,
                                                   const float* __restrict__ z2,
                                                   __hip_bfloat16* __restrict__ z1n,
                                                   __hip_bfloat16* __restrict__ z2n,
                                                   float* __restrict__ pos) {
    int row  = (blockIdx.x * 256 + threadIdx.x) >> 6;   // one wave per row
    int lane = threadIdx.x & 63;
    int c = lane * 2;
    const float2 v1 = *(const float2*)(z1 + row * FDIM + c);
    const float2 v2 = *(const float2*)(z2 + row * FDIM + c);
    float s1 = v1.x * v1.x + v1.y * v1.y;
    float s2 = v2.x * v2.x + v2.y * v2.y;
    for (int m = 32; m > 0; m >>= 1) { s1 += __shfl_xor(s1, m); s2 += __shfl_xor(s2, m); }
    float inv1 = 1.0f / fmaxf(sqrtf(s1), 1e-12f);
    float inv2 = 1.0f / fmaxf(sqrtf(s2), 1e-12f);
    float a0 = v1.x * inv1, a1 = v1.y * inv1;
    float b0 = v2.x * inv2, b1 = v2.y * inv2;
    // S' = (log2e * z1n) . z2n  ->  2^S' == e^S in the row-sum
    z1n[row * FDIM + c]     = __float2bfloat16(a0 * LOG2E);
    z1n[row * FDIM + c + 1] = __float2bfloat16(a1 * LOG2E);
    z2n[row * FDIM + c]     = __float2bfloat16(b0);
    z2n[row * FDIM + c + 1] = __float2bfloat16(b1);
    float p = a0 * b0 + a1 * b1;                        // unscaled positive logit
    for (int m = 32; m > 0; m >>= 1) p += __shfl_xor(p, m);
    if (lane == 0) pos[row] = p;
}

// ---------------- Kernel B: persistent row-panel GEMM + exp2 + row-sum ----------------
// 256 threads / 4 waves. Block = 128 rows x 512 cols (8 tiles of 64 cols).
// Each wave: 32 rows x 64 cols per tile. A (32x128/wave) in regs (32 VGPR);
// B tile (64x128 = 16KB) double-buffered in LDS via global_load_lds with
// pre-swizzled source. Partials -> rsPart, no atomics.
// Register budget: a 32 + acc 32 + b 16 + rowsum 8 + addr ~20 = ~110 < 128.
__global__ __launch_bounds__(256, 4) void simclr_gemm(const __hip_bfloat16* __restrict__ z1n,
                                                      const __hip_bfloat16* __restrict__ z2n,
                                                      float* __restrict__ rsPart) {
    __shared__ unsigned char smem[32768];   // two 16KB B buffers
    const int tid = threadIdx.x;
    const int wid = tid >> 6, lane = tid & 63;
    const int lq = lane >> 4, lr = lane & 15;
    const int rowBase = blockIdx.y * 128;
    const int colBase = blockIdx.x * (NT * BN);

    const unsigned short* g1 = (const unsigned short*)z1n;
    const unsigned short* g2 = (const unsigned short*)z2n;

    // stage tile 0 into buf0: instr (wid,j) covers B-rows [(wid*4+j)*4, +4)
#pragma unroll
    for (int j = 0; j < 4; ++j) {
        int rl = (wid * 4 + j) * 4 + lq;
        const unsigned short* gp = g2 + (size_t)(colBase + rl) * FDIM + (lr ^ (rl & 7)) * 8;
        GLOAD_LDS(gp, smem + wid * 4096 + j * 1024);
    }

    // A fragments -> registers (once): wave's 32 rows x 128 k
    bf16x8 a[2][4];
#pragma unroll
    for (int m = 0; m < 2; ++m) {
        int rA = rowBase + wid * 32 + m * 16 + lr;
        const unsigned short* rp = g1 + (size_t)rA * FDIM + lq * 8;
#pragma unroll
        for (int kk = 0; kk < 4; ++kk)
            a[m][kk] = *(const bf16x8*)(rp + kk * 32);
    }

    float rowsum[2][4] = {};

    for (int t = 0; t < NT; ++t) {
        __syncthreads();                 // stage t complete (vmcnt drain); reads of t-1 done
        const int cur = (t & 1) * 16384;
        if (t + 1 < NT) {
            const int colT = colBase + (t + 1) * BN;
            const int nxt = ((t + 1) & 1) * 16384;
#pragma unroll
            for (int j = 0; j < 4; ++j) {
                int rl = (wid * 4 + j) * 4 + lq;
                const unsigned short* gp = g2 + (size_t)(colT + rl) * FDIM + (lr ^ (rl & 7)) * 8;
                GLOAD_LDS(gp, smem + nxt + wid * 4096 + j * 1024);
            }
        }
        f32x4 acc[2][4] = {};
#pragma unroll
        for (int kk = 0; kk < 4; ++kk) {
            bf16x8 b[4];
            const int kByte = kk * 64 + lq * 16;
#pragma unroll
            for (int n = 0; n < 4; ++n) {
                int rB = n * 16 + lr;
                b[n] = *(const bf16x8*)(smem + cur + rB * 256 + (kByte ^ ((rB & 7) << 4)));
            }
#pragma unroll
            for (int m = 0; m < 2; ++m)
#pragma unroll
                for (int n = 0; n < 4; ++n)
                    acc[m][n] = __builtin_amdgcn_mfma_f32_16x16x32_bf16(a[m][kk], b[n], acc[m][n], 0, 0, 0);
        }
        // rows: wid*32 + m*16 + lq*4 + r; cols: n*16 + lr. 2^acc == e^S.
#pragma unroll
        for (int m = 0; m < 2; ++m)
#pragma unroll
            for (int r = 0; r < 4; ++r)
                rowsum[m][r] += exp2f(acc[m][0][r]) + exp2f(acc[m][1][r]) +
                                exp2f(acc[m][2][r]) + exp2f(acc[m][3][r]);
    }

    // reduce across the 16 col-lanes; one plain store per row (no atomics)
#pragma unroll
    for (int m = 0; m < 2; ++m)
#pragma unroll
        for (int r = 0; r < 4; ++r) {
            float s = rowsum[m][r];
            s += __shfl_xor(s, 1); s += __shfl_xor(s, 2);
            s += __shfl_xor(s, 4); s += __shfl_xor(s, 8);
            if (lr == 0)
                rsPart[blockIdx.x * B_ROWS + rowBase + wid * 32 + m * 16 + lq * 4 + r] = s;
        }
}

// ---------------- Kernel C: loss = mean(log(rowsum) - pos) ----------------
__global__ __launch_bounds__(256) void simclr_finish(const float* __restrict__ rsPart,
                                                     const float* __restrict__ pos,
                                                     float* __restrict__ out) {
    __shared__ float red[4];
    int i = blockIdx.x * 256 + threadIdx.x;   // one thread per row, 32 blocks
    float R = 0.0f;
#pragma unroll
    for (int c = 0; c < NCHUNK; ++c) R += rsPart[c * B_ROWS + i];
    float s = logf(R) - pos[i];
    for (int m = 32; m > 0; m >>= 1) s += __shfl_xor(s, m);
    if ((threadIdx.x & 63) == 0) red[threadIdx.x >> 6] = s;
    __syncthreads();
    if (threadIdx.x == 0) {
        float v = (red[0] + red[1]) + (red[2] + red[3]);
        atomicAdd(out, v * (1.0f / (float)B_ROWS));
    }
}

extern "C" void kernel_launch(void* const* d_in, const int* in_sizes, int n_in,
                              void* d_out, int out_size, void* d_ws, size_t ws_size,
                              hipStream_t stream) {
    const float* z1 = (const float*)d_in[0];
    const float* z2 = (const float*)d_in[1];
    float* out = (float*)d_out;
    char* ws = (char*)d_ws;

    __hip_bfloat16* z1n = (__hip_bfloat16*)ws;                       // 2 MB
    __hip_bfloat16* z2n = (__hip_bfloat16*)(ws + 2097152);           // 2 MB
    float* pos          = (float*)(ws + 4194304);                    // 32 KB
    float* rsPart       = (float*)(ws + 4194304 + 32768);            // 512 KB

    hipMemsetAsync(out, 0, sizeof(float), stream);
    simclr_norm<<<B_ROWS / 4, 256, 0, stream>>>(z1, z2, z1n, z2n, pos);
    simclr_gemm<<<dim3(NCHUNK, 64), 256, 0, stream>>>(z1n, z2n, rsPart);
    simclr_finish<<<B_ROWS / 256, 256, 0, stream>>>(rsPart, pos, out);
}

// Round 5
// 61.281 us; speedup vs baseline: 3.1293x; 3.1293x over previous
//
#include <hip/hip_runtime.h>
#include <hip/hip_bf16.h>

typedef __attribute__((ext_vector_type(8))) short bf16x8;
typedef __attribute__((ext_vector_type(4))) float f32x4;

#define B_ROWS 8192
#define FDIM 128
#define BN 64            // cols per tile
#define NT 8             // tiles per block -> 512 cols per chunk
#define NCHUNK 16        // 8192 / 512

#define GLOAD_LDS(gp, lp) __builtin_amdgcn_global_load_lds( \
    (const __attribute__((address_space(1))) unsigned*)(gp), \
    (__attribute__((address_space(3))) unsigned*)(lp), 16, 0, 0)

#define LOG2E 1.4426950408889634f

// ---------------- Kernel A: normalize; z1n scaled by log2(e); pos[i] exact ----------------
__global__ __launch_bounds__(256) void simclr_norm(const float* __restrict__ z1,
                                                   const float* __restrict__ z2,
                                                   __hip_bfloat16* __restrict__ z1n,
                                                   __hip_bfloat16* __restrict__ z2n,
                                                   float* __restrict__ pos) {
    int row  = (blockIdx.x * 256 + threadIdx.x) >> 6;   // one wave per row
    int lane = threadIdx.x & 63;
    int c = lane * 2;
    const float2 v1 = *(const float2*)(z1 + row * FDIM + c);
    const float2 v2 = *(const float2*)(z2 + row * FDIM + c);
    float s1 = v1.x * v1.x + v1.y * v1.y;
    float s2 = v2.x * v2.x + v2.y * v2.y;
    for (int m = 32; m > 0; m >>= 1) { s1 += __shfl_xor(s1, m); s2 += __shfl_xor(s2, m); }
    float inv1 = 1.0f / fmaxf(sqrtf(s1), 1e-12f);
    float inv2 = 1.0f / fmaxf(sqrtf(s2), 1e-12f);
    float a0 = v1.x * inv1, a1 = v1.y * inv1;
    float b0 = v2.x * inv2, b1 = v2.y * inv2;
    // S' = (log2e * z1n) . z2n  ->  2^S' == e^S in the row-sum
    z1n[row * FDIM + c]     = __float2bfloat16(a0 * LOG2E);
    z1n[row * FDIM + c + 1] = __float2bfloat16(a1 * LOG2E);
    z2n[row * FDIM + c]     = __float2bfloat16(b0);
    z2n[row * FDIM + c + 1] = __float2bfloat16(b1);
    float p = a0 * b0 + a1 * b1;                        // unscaled positive logit
    for (int m = 32; m > 0; m >>= 1) p += __shfl_xor(p, m);
    if (lane == 0) pos[row] = p;
}

// ---------------- Kernel B: persistent row-panel GEMM + exp2 + row-sum ----------------
// 256 threads / 4 waves. Block = 128 rows x 512 cols (8 tiles of 64 cols).
// Each wave: 32 rows x 64 cols per tile. A (32x128/wave) in regs (32 VGPR);
// B tile (64x128 = 16KB) double-buffered in LDS via global_load_lds with
// pre-swizzled source. Partials -> rsPart, no atomics.
// NOTE: plain __launch_bounds__(256) — a min-waves 2nd arg makes the allocator
// cap arch VGPRs at 64 and spill the MFMA loop to scratch (rounds 3/4:
// WRITE_SIZE 190->373 MB of pure spill traffic). Round 1 showed the default
// allocator picks ~88 VGPR + AGPR acc with no spill.
__global__ __launch_bounds__(256) void simclr_gemm(const __hip_bfloat16* __restrict__ z1n,
                                                   const __hip_bfloat16* __restrict__ z2n,
                                                   float* __restrict__ rsPart) {
    __shared__ unsigned char smem[32768];   // two 16KB B buffers
    const int tid = threadIdx.x;
    const int wid = tid >> 6, lane = tid & 63;
    const int lq = lane >> 4, lr = lane & 15;
    const int rowBase = blockIdx.y * 128;
    const int colBase = blockIdx.x * (NT * BN);

    const unsigned short* g1 = (const unsigned short*)z1n;
    const unsigned short* g2 = (const unsigned short*)z2n;

    // stage tile 0 into buf0: instr (wid,j) covers B-rows [(wid*4+j)*4, +4)
#pragma unroll
    for (int j = 0; j < 4; ++j) {
        int rl = (wid * 4 + j) * 4 + lq;
        const unsigned short* gp = g2 + (size_t)(colBase + rl) * FDIM + (lr ^ (rl & 7)) * 8;
        GLOAD_LDS(gp, smem + wid * 4096 + j * 1024);
    }

    // A fragments -> registers (once): wave's 32 rows x 128 k
    bf16x8 a[2][4];
#pragma unroll
    for (int m = 0; m < 2; ++m) {
        int rA = rowBase + wid * 32 + m * 16 + lr;
        const unsigned short* rp = g1 + (size_t)rA * FDIM + lq * 8;
#pragma unroll
        for (int kk = 0; kk < 4; ++kk)
            a[m][kk] = *(const bf16x8*)(rp + kk * 32);
    }

    float rowsum[2][4] = {};

    for (int t = 0; t < NT; ++t) {
        __syncthreads();                 // stage t complete (vmcnt drain); reads of t-1 done
        const int cur = (t & 1) * 16384;
        if (t + 1 < NT) {
            const int colT = colBase + (t + 1) * BN;
            const int nxt = ((t + 1) & 1) * 16384;
#pragma unroll
            for (int j = 0; j < 4; ++j) {
                int rl = (wid * 4 + j) * 4 + lq;
                const unsigned short* gp = g2 + (size_t)(colT + rl) * FDIM + (lr ^ (rl & 7)) * 8;
                GLOAD_LDS(gp, smem + nxt + wid * 4096 + j * 1024);
            }
        }
        f32x4 acc[2][4] = {};
#pragma unroll
        for (int kk = 0; kk < 4; ++kk) {
            bf16x8 b[4];
            const int kByte = kk * 64 + lq * 16;
#pragma unroll
            for (int n = 0; n < 4; ++n) {
                int rB = n * 16 + lr;
                b[n] = *(const bf16x8*)(smem + cur + rB * 256 + (kByte ^ ((rB & 7) << 4)));
            }
#pragma unroll
            for (int m = 0; m < 2; ++m)
#pragma unroll
                for (int n = 0; n < 4; ++n)
                    acc[m][n] = __builtin_amdgcn_mfma_f32_16x16x32_bf16(a[m][kk], b[n], acc[m][n], 0, 0, 0);
        }
        // rows: wid*32 + m*16 + lq*4 + r; cols: n*16 + lr. 2^acc == e^S.
#pragma unroll
        for (int m = 0; m < 2; ++m)
#pragma unroll
            for (int r = 0; r < 4; ++r)
                rowsum[m][r] += exp2f(acc[m][0][r]) + exp2f(acc[m][1][r]) +
                                exp2f(acc[m][2][r]) + exp2f(acc[m][3][r]);
    }

    // reduce across the 16 col-lanes; one plain store per row (no atomics)
#pragma unroll
    for (int m = 0; m < 2; ++m)
#pragma unroll
        for (int r = 0; r < 4; ++r) {
            float s = rowsum[m][r];
            s += __shfl_xor(s, 1); s += __shfl_xor(s, 2);
            s += __shfl_xor(s, 4); s += __shfl_xor(s, 8);
            if (lr == 0)
                rsPart[blockIdx.x * B_ROWS + rowBase + wid * 32 + m * 16 + lq * 4 + r] = s;
        }
}

// ---------------- Kernel C: loss = mean(log(rowsum) - pos) ----------------
__global__ __launch_bounds__(256) void simclr_finish(const float* __restrict__ rsPart,
                                                     const float* __restrict__ pos,
                                                     float* __restrict__ out) {
    __shared__ float red[4];
    int i = blockIdx.x * 256 + threadIdx.x;   // one thread per row, 32 blocks
    float R = 0.0f;
#pragma unroll
    for (int c = 0; c < NCHUNK; ++c) R += rsPart[c * B_ROWS + i];
    float s = logf(R) - pos[i];
    for (int m = 32; m > 0; m >>= 1) s += __shfl_xor(s, m);
    if ((threadIdx.x & 63) == 0) red[threadIdx.x >> 6] = s;
    __syncthreads();
    if (threadIdx.x == 0) {
        float v = (red[0] + red[1]) + (red[2] + red[3]);
        atomicAdd(out, v * (1.0f / (float)B_ROWS));
    }
}

extern "C" void kernel_launch(void* const* d_in, const int* in_sizes, int n_in,
                              void* d_out, int out_size, void* d_ws, size_t ws_size,
                              hipStream_t stream) {
    const float* z1 = (const float*)d_in[0];
    const float* z2 = (const float*)d_in[1];
    float* out = (float*)d_out;
    char* ws = (char*)d_ws;

    __hip_bfloat16* z1n = (__hip_bfloat16*)ws;                       // 2 MB
    __hip_bfloat16* z2n = (__hip_bfloat16*)(ws + 2097152);           // 2 MB
    float* pos          = (float*)(ws + 4194304);                    // 32 KB
    float* rsPart       = (float*)(ws + 4194304 + 32768);            // 512 KB

    hipMemsetAsync(out, 0, sizeof(float), stream);
    simclr_norm<<<B_ROWS / 4, 256, 0, stream>>>(z1, z2, z1n, z2n, pos);
    simclr_gemm<<<dim3(NCHUNK, 64), 256, 0, stream>>>(z1n, z2n, rsPart);
    simclr_finish<<<B_ROWS / 256, 256, 0, stream>>>(rsPart, pos, out);
}